// Round 2
// baseline (162.404 us; speedup 1.0000x reference)
//
#include <hip/hip_runtime.h>
#include <math.h>

#define SEGN 5
#define SEG_LEN 100
#define WLEN 500
#define WSTEP 250
#define ALPHA_C (-0.01f)
#define BLOCK 256
#define NW 64                      // windows per block (one per lane)
#define SPAN (NW * WSTEP + WSTEP)  // 16250 floats staged per block

// Accumulate NP pairs of x elements starting at (even) element E0, all inside
// segment I. HASM/HASP: whether y-neighbor segments I-1 / I+1 exist.
// Fully unrolled -> S offsets are compile-time -> scalar (SMEM) loads.
#define RUN_PAIRS(E0, NP, I, HASM, HASP)                                       \
  _Pragma("unroll")                                                            \
  for (int m = 0; m < (NP); ++m) {                                             \
    const int e = (E0) + 2 * m;                                                \
    const int s = e - 100 * (I);                                               \
    const float2 xv = *reinterpret_cast<const float2*>(&sX[xoff + e]);         \
    xx[I] = fmaf(xv.x, xv.x, fmaf(xv.y, xv.y, xx[I]));                         \
    if (HASM) {                                                                \
      const float2 ym =                                                        \
          *reinterpret_cast<const float2*>(&S[100 * ((I) - 1) + s]);           \
      xy[I][(I) > 0 ? (I) - 1 : 0] =                                           \
          fmaf(xv.x, ym.x, fmaf(xv.y, ym.y, xy[I][(I) > 0 ? (I) - 1 : 0]));    \
    }                                                                          \
    {                                                                          \
      const float2 y0 = *reinterpret_cast<const float2*>(&S[100 * (I) + s]);   \
      xy[I][I] = fmaf(xv.x, y0.x, fmaf(xv.y, y0.y, xy[I][I]));                 \
    }                                                                          \
    if (HASP) {                                                                \
      const float2 yp =                                                        \
          *reinterpret_cast<const float2*>(&S[100 * ((I) + 1) + s]);           \
      xy[I][(I) < 4 ? (I) + 1 : 4] =                                           \
          fmaf(xv.x, yp.x, fmaf(xv.y, yp.y, xy[I][(I) < 4 ? (I) + 1 : 4]));    \
    }                                                                          \
  }

#define RUN_ONE(E, I, HASM, HASP)                                              \
  {                                                                            \
    const int s = (E) - 100 * (I);                                             \
    const float xv = sX[xoff + (E)];                                           \
    xx[I] = fmaf(xv, xv, xx[I]);                                               \
    if (HASM)                                                                  \
      xy[I][(I) > 0 ? (I) - 1 : 0] =                                           \
          fmaf(xv, S[100 * ((I) - 1) + s], xy[I][(I) > 0 ? (I) - 1 : 0]);      \
    xy[I][I] = fmaf(xv, S[100 * (I) + s], xy[I][I]);                           \
    if (HASP)                                                                  \
      xy[I][(I) < 4 ? (I) + 1 : 4] =                                           \
          fmaf(xv, S[100 * ((I) + 1) + s], xy[I][(I) < 4 ? (I) + 1 : 4]);      \
  }

__global__ __launch_bounds__(BLOCK)
void softmin_dtw_kernel(const float* __restrict__ x, const float* __restrict__ S,
                        float* __restrict__ out, long long Q, int W,
                        float inv_W) {
  __shared__ __align__(16) float sX[SPAN];  // also reused for partials (4608 floats)

  const int tid = threadIdx.x;
  const int t = tid >> 6;   // wave id = window-quarter index (wave-uniform)
  const int w = tid & 63;   // local window index (lane)

  // ---- Stage block's x-span into LDS, fully coalesced float4 ----
  const long long baseg = (long long)blockIdx.x * (NW * WSTEP);
  #pragma unroll 4
  for (int idx = tid; idx < SPAN / 4; idx += BLOCK) {  // 4062 float4s
    const long long g = baseg + 4LL * idx;
    float4 v;
    if (g + 4 <= Q) {
      v = *reinterpret_cast<const float4*>(&x[g]);
    } else {
      v.x = (g     < Q) ? x[g]     : 0.f;
      v.y = (g + 1 < Q) ? x[g + 1] : 0.f;
      v.z = (g + 2 < Q) ? x[g + 2] : 0.f;
      v.w = (g + 3 < Q) ? x[g + 3] : 0.f;
    }
    *reinterpret_cast<float4*>(&sX[4 * idx]) = v;
  }
  if (tid < SPAN - 4 * (SPAN / 4)) {  // 2 tail floats (16248, 16249)
    const int idx = 4 * (SPAN / 4) + tid;
    const long long g = baseg + idx;
    sX[idx] = (g < Q) ? x[g] : 0.f;
  }
  __syncthreads();

  // ---- Compute: wave t handles elements [125t, 125t+125) of window w ----
  const int xoff = w * WSTEP;
  float xx[SEGN] = {0.f, 0.f, 0.f, 0.f, 0.f};
  float xy[SEGN][SEGN] = {{0.f}};

  if (t == 0) {
    RUN_PAIRS(0, 50, 0, 0, 1);
    RUN_PAIRS(100, 12, 1, 1, 1);
    RUN_ONE(124, 1, 1, 1);
  } else if (t == 1) {
    RUN_ONE(125, 1, 1, 1);
    RUN_PAIRS(126, 37, 1, 1, 1);
    RUN_PAIRS(200, 25, 2, 1, 1);
  } else if (t == 2) {
    RUN_PAIRS(250, 25, 2, 1, 1);
    RUN_PAIRS(300, 37, 3, 1, 1);
    RUN_ONE(374, 3, 1, 1);
  } else {
    RUN_ONE(375, 3, 1, 1);
    RUN_PAIRS(376, 12, 3, 1, 1);
    RUN_PAIRS(400, 50, 4, 1, 0);
  }

  // ---- Write 18 partials per (wave, window) into LDS (alias sX) ----
  __syncthreads();  // all waves done reading sX
  {
    const float vals[18] = {xx[0], xx[1], xx[2], xx[3], xx[4],
                            xy[0][0], xy[0][1],
                            xy[1][0], xy[1][1], xy[1][2],
                            xy[2][1], xy[2][2], xy[2][3],
                            xy[3][2], xy[3][3], xy[3][4],
                            xy[4][3], xy[4][4]};
    #pragma unroll
    for (int a = 0; a < 18; ++a) sX[(a * 4 + t) * 64 + w] = vals[a];
  }
  __syncthreads();

  // ---- Wave 0: reduce partials, DTW, exp, block sum, one atomic ----
  if (tid < 64) {
    const int wl = tid;
    float A[18];
    #pragma unroll
    for (int a = 0; a < 18; ++a)
      A[a] = sX[(a * 4 + 0) * 64 + wl] + sX[(a * 4 + 1) * 64 + wl] +
             sX[(a * 4 + 2) * 64 + wl] + sX[(a * 4 + 3) * 64 + wl];

    // yy[j] from S directly (uniform, L1/SMEM-cached)
    float yy[SEGN];
    #pragma unroll
    for (int j = 0; j < SEGN; ++j) {
      float a = 0.f;
      #pragma unroll
      for (int s2 = 0; s2 < SEG_LEN / 2; ++s2) {
        const float2 v = *reinterpret_cast<const float2*>(&S[j * SEG_LEN + 2 * s2]);
        a = fmaf(v.x, v.x, fmaf(v.y, v.y, a));
      }
      yy[j] = a;
    }

    float xi = 0.f;
    const long long wg = (long long)blockIdx.x * NW + wl;
    if (wg < W) {
      const float xx0 = A[0], xx1 = A[1], xx2 = A[2], xx3 = A[3], xx4 = A[4];
      const float C00 = xx0 + yy[0] - 2.f * A[5];
      const float C01 = xx0 + yy[1] - 2.f * A[6];
      const float C10 = xx1 + yy[0] - 2.f * A[7];
      const float C11 = xx1 + yy[1] - 2.f * A[8];
      const float C12 = xx1 + yy[2] - 2.f * A[9];
      const float C21 = xx2 + yy[1] - 2.f * A[10];
      const float C22 = xx2 + yy[2] - 2.f * A[11];
      const float C23 = xx2 + yy[3] - 2.f * A[12];
      const float C32 = xx3 + yy[2] - 2.f * A[13];
      const float C33 = xx3 + yy[3] - 2.f * A[14];
      const float C34 = xx3 + yy[4] - 2.f * A[15];
      const float C43 = xx4 + yy[3] - 2.f * A[16];
      const float C44 = xx4 + yy[4] - 2.f * A[17];

      const float c11 = C00;
      const float c12 = C01 + c11;
      const float c21 = C10 + c11;
      const float c22 = C11 + fminf(fminf(c12, c21), c11);
      const float c23 = C12 + fminf(c22, c12);
      const float c32 = C21 + fminf(c22, c21);
      const float c33 = C22 + fminf(fminf(c23, c32), c22);
      const float c34 = C23 + fminf(c33, c23);
      const float c43 = C32 + fminf(c33, c32);
      const float c44 = C33 + fminf(fminf(c34, c43), c33);
      const float c45 = C34 + fminf(c44, c34);
      const float c54 = C43 + fminf(c44, c43);
      const float c55 = C44 + fminf(fminf(c45, c54), c44);

      xi = expf(ALPHA_C * sqrtf(fmaxf(c55, 0.f)));
    }

    #pragma unroll
    for (int off = 32; off > 0; off >>= 1) xi += __shfl_down(xi, off);
    if (wl == 0) atomicAdd(out, xi * inv_W);
  }
}

extern "C" void kernel_launch(void* const* d_in, const int* in_sizes, int n_in,
                              void* d_out, int out_size, void* d_ws, size_t ws_size,
                              hipStream_t stream) {
  const float* x = (const float*)d_in[0];
  const float* S = (const float*)d_in[1];
  float* out = (float*)d_out;

  const long long Q = in_sizes[0];
  const int L = in_sizes[1];   // 500
  const int step = L / 2;      // 250
  const long long n = Q - L;
  const int W = (int)((n + step - 1) / step);  // 79998

  hipMemsetAsync(out, 0, sizeof(float), stream);

  const int blocks = (W + NW - 1) / NW;  // 1250
  softmin_dtw_kernel<<<blocks, BLOCK, 0, stream>>>(x, S, out, Q, W,
                                                   1.0f / (float)W);
}

// Round 3
// 132.013 us; speedup vs baseline: 1.2302x; 1.2302x over previous
//
#include <hip/hip_runtime.h>
#include <math.h>

#define ALPHA_C (-0.01f)
#define BLOCK 256
#define NB 256          // 50-blocks per block (one per thread)
#define NWIN 50         // windows fully resolved per block
#define SPANF (NB * 50) // 12800 floats staged

__global__ __launch_bounds__(BLOCK)
void softmin_dtw_kernel(const float* __restrict__ x, const float* __restrict__ S,
                        float* __restrict__ out, long long Q, int W,
                        float inv_W) {
  __shared__ __align__(16) float sX[SPANF];  // aliased for combine buffers later
  __shared__ __align__(16) float sS[500];
  __shared__ float sYY[5];

  const int tid = threadIdx.x;
  const int g = blockIdx.x;
  const long long base = 12500LL * g;  // block g covers 50-blocks b = 250g + tid

  // ---- Stage S (2 KB) and x span (50 KB), coalesced float4 ----
  if (tid < 125)
    *reinterpret_cast<float4*>(&sS[tid * 4]) =
        *reinterpret_cast<const float4*>(&S[tid * 4]);

  #pragma unroll
  for (int r = 0; r < SPANF / 4 / BLOCK + 1; ++r) {  // 13 rounds, last partial
    const int idx = r * BLOCK + tid;
    if (idx < SPANF / 4) {
      const long long gp = base + 4LL * idx;
      float4 v;
      if (gp + 4 <= Q) {
        v = *reinterpret_cast<const float4*>(&x[gp]);
      } else {
        v.x = (gp     < Q) ? x[gp]     : 0.f;
        v.y = (gp + 1 < Q) ? x[gp + 1] : 0.f;
        v.z = (gp + 2 < Q) ? x[gp + 2] : 0.f;
        v.w = (gp + 3 < Q) ? x[gp + 3] : 0.f;
      }
      *reinterpret_cast<float4*>(&sX[4 * idx]) = v;
    }
  }
  __syncthreads();

  // yy[j] (5 threads; consumed after a later barrier)
  if (tid < 5) {
    float a = 0.f;
    #pragma unroll 10
    for (int s = 0; s < 100; s += 2) {
      const float2 v = *reinterpret_cast<const float2*>(&sS[tid * 100 + s]);
      a = fmaf(v.x, v.x, fmaf(v.y, v.y, a));
    }
    sYY[tid] = a;
  }

  // ---- Per-50-block partial dots: compact loop ----
  const int i0 = (3 * tid) % 5;        // role-0 segment center
  const int i1 = (i0 + 2) % 5;        // role-1 segment center
  const int a0 = (i0 > 0 ? i0 - 1 : 0) * 100;
  const int a1 = i0 * 100;
  const int a2 = (i0 < 4 ? i0 + 1 : 4) * 100;
  const int b0 = (i1 > 0 ? i1 - 1 : 0) * 100 + 50;
  const int b1 = i1 * 100 + 50;
  const int b2 = (i1 < 4 ? i1 + 1 : 4) * 100 + 50;

  float sq = 0.f, A0 = 0.f, A1 = 0.f, A2 = 0.f, B0 = 0.f, B1 = 0.f, B2 = 0.f;
  const int xb = tid * 50;
  #pragma unroll 5
  for (int t = 0; t < 50; t += 2) {
    const float2 xv = *reinterpret_cast<const float2*>(&sX[xb + t]);
    float2 y;
    sq = fmaf(xv.x, xv.x, fmaf(xv.y, xv.y, sq));
    y = *reinterpret_cast<const float2*>(&sS[a0 + t]);
    A0 = fmaf(xv.x, y.x, fmaf(xv.y, y.y, A0));
    y = *reinterpret_cast<const float2*>(&sS[a1 + t]);
    A1 = fmaf(xv.x, y.x, fmaf(xv.y, y.y, A1));
    y = *reinterpret_cast<const float2*>(&sS[a2 + t]);
    A2 = fmaf(xv.x, y.x, fmaf(xv.y, y.y, A2));
    y = *reinterpret_cast<const float2*>(&sS[b0 + t]);
    B0 = fmaf(xv.x, y.x, fmaf(xv.y, y.y, B0));
    y = *reinterpret_cast<const float2*>(&sS[b1 + t]);
    B1 = fmaf(xv.x, y.x, fmaf(xv.y, y.y, B1));
    y = *reinterpret_cast<const float2*>(&sS[b2 + t]);
    B2 = fmaf(xv.x, y.x, fmaf(xv.y, y.y, B2));
  }

  // ---- Neighbor combine via LDS (alias sX after all reads done) ----
  __syncthreads();
  float* exch = sX;                 // [256][4]: {sq, B0, B1, B2}
  float* cw   = sX + 4 * BLOCK;     // [50][5][4]: {xx, xy[i][i-1], xy[i][i], xy[i][i+1]}
  {
    float4 ex;
    ex.x = sq; ex.y = B0; ex.z = B1; ex.w = B2;
    *reinterpret_cast<float4*>(&exch[tid * 4]) = ex;
  }
  __syncthreads();
  if (tid < BLOCK - 1) {
    const float4 nx = *reinterpret_cast<const float4*>(&exch[(tid + 1) * 4]);
    const int lw = (tid - 2 * i0) / 5;  // exact division (tid-2*i0 ≡ 0 mod 5)
    const long long w0 = 50LL * g + lw;
    if (lw >= 0 && lw < NWIN && w0 < W) {
      float* c = &cw[(lw * 5 + i0) * 4];
      c[0] = sq + nx.x;
      c[1] = A0 + nx.y;
      c[2] = A1 + nx.z;
      c[3] = A2 + nx.w;
    }
  }
  __syncthreads();

  // ---- DTW + exp per window (threads 0..49, all in wave 0) ----
  float xi = 0.f;
  if (tid < NWIN) {
    const long long w = 50LL * g + tid;
    if (w < W) {
      const float yy0 = sYY[0], yy1 = sYY[1], yy2 = sYY[2], yy3 = sYY[3],
                  yy4 = sYY[4];
      const float* c0 = &cw[(tid * 5 + 0) * 4];
      const float* c1 = &cw[(tid * 5 + 1) * 4];
      const float* c2 = &cw[(tid * 5 + 2) * 4];
      const float* c3 = &cw[(tid * 5 + 3) * 4];
      const float* c4 = &cw[(tid * 5 + 4) * 4];

      const float C00 = c0[0] + yy0 - 2.f * c0[2];
      const float C01 = c0[0] + yy1 - 2.f * c0[3];
      const float C10 = c1[0] + yy0 - 2.f * c1[1];
      const float C11 = c1[0] + yy1 - 2.f * c1[2];
      const float C12 = c1[0] + yy2 - 2.f * c1[3];
      const float C21 = c2[0] + yy1 - 2.f * c2[1];
      const float C22 = c2[0] + yy2 - 2.f * c2[2];
      const float C23 = c2[0] + yy3 - 2.f * c2[3];
      const float C32 = c3[0] + yy2 - 2.f * c3[1];
      const float C33 = c3[0] + yy3 - 2.f * c3[2];
      const float C34 = c3[0] + yy4 - 2.f * c3[3];
      const float C43 = c4[0] + yy3 - 2.f * c4[1];
      const float C44 = c4[0] + yy4 - 2.f * c4[2];

      const float c11v = C00;
      const float c12v = C01 + c11v;
      const float c21v = C10 + c11v;
      const float c22v = C11 + fminf(fminf(c12v, c21v), c11v);
      const float c23v = C12 + fminf(c22v, c12v);
      const float c32v = C21 + fminf(c22v, c21v);
      const float c33v = C22 + fminf(fminf(c23v, c32v), c22v);
      const float c34v = C23 + fminf(c33v, c23v);
      const float c43v = C32 + fminf(c33v, c32v);
      const float c44v = C33 + fminf(fminf(c34v, c43v), c33v);
      const float c45v = C34 + fminf(c44v, c34v);
      const float c54v = C43 + fminf(c44v, c43v);
      const float c55v = C44 + fminf(fminf(c45v, c54v), c44v);

      xi = expf(ALPHA_C * sqrtf(fmaxf(c55v, 0.f)));
    }
  }

  // Only wave 0 holds nonzero xi; reduce there, one atomic per block.
  if (tid < 64) {
    #pragma unroll
    for (int off = 32; off > 0; off >>= 1) xi += __shfl_down(xi, off);
    if (tid == 0) atomicAdd(out, xi * inv_W);
  }
}

extern "C" void kernel_launch(void* const* d_in, const int* in_sizes, int n_in,
                              void* d_out, int out_size, void* d_ws, size_t ws_size,
                              hipStream_t stream) {
  const float* x = (const float*)d_in[0];
  const float* S = (const float*)d_in[1];
  float* out = (float*)d_out;

  const long long Q = in_sizes[0];
  const int L = in_sizes[1];   // 500
  const int step = L / 2;      // 250
  const long long n = Q - L;
  const int W = (int)((n + step - 1) / step);  // 79998

  hipMemsetAsync(out, 0, sizeof(float), stream);

  const int blocks = (W + NWIN - 1) / NWIN;  // 1600
  softmin_dtw_kernel<<<blocks, BLOCK, 0, stream>>>(x, S, out, Q, W,
                                                   1.0f / (float)W);
}